// Round 2
// baseline (529.604 us; speedup 1.0000x reference)
//
#include <hip/hip_runtime.h>
#include <hip/hip_bf16.h>

// MoE gate: logits = r @ W^T + b ; soft = softmax(logits) ; hard = top8-renorm
// r: (32768, 2048) fp32, W: (64, 2048) fp32, b: (64,) fp32
// d_out: [hard (32768*64) | soft (32768*64)] fp32
//
// Precision: top-8 mask is discrete -> must match fp32-class logits, bf16 GEMM
// rank-flips (round-1 absmax 0.108 = one 8th-weight/topsum). Use exact bf16^3
// split (fp32 == h1+h2+h3 exactly) on both operands, keep the 6 MFMA product
// terms >= 2^-16; dropped terms <= 2^-26. Logit error ~2e-6 (fp32 class).

#define D_DIM 2048
#define E_DIM 64
#define B_DIM 32768
#define TOPK 8

typedef __bf16 bf16x8 __attribute__((ext_vector_type(8)));
typedef float f32x4 __attribute__((ext_vector_type(4)));

// ---- prep: W fp32 -> 3 bf16 splits in workspace (3 * 131072 elems = 768 KB) ----
__global__ __launch_bounds__(256) void w_split3(const float* __restrict__ W,
                                                __bf16* __restrict__ W1,
                                                __bf16* __restrict__ W2,
                                                __bf16* __restrict__ W3) {
    int i = (blockIdx.x * 256 + threadIdx.x) * 8;  // 64 blocks
    bf16x8 o1, o2, o3;
    #pragma unroll
    for (int j = 0; j < 8; ++j) {
        float x  = W[i + j];
        __bf16 h1 = (__bf16)x;
        float r1 = x - (float)h1;          // exact
        __bf16 h2 = (__bf16)r1;
        float r2 = r1 - (float)h2;         // exact
        __bf16 h3 = (__bf16)r2;            // exact residual (<=8 bits left)
        o1[j] = h1; o2[j] = h2; o3[j] = h3;
    }
    *(bf16x8*)(W1 + i) = o1;
    *(bf16x8*)(W2 + i) = o2;
    *(bf16x8*)(W3 + i) = o3;
}

// ---- main: 6-term split GEMM (mfma 16x16x32 bf16) + fused softmax/top-8 ----
// Block = 256 thr = 4 waves; wave owns 16 rows x 64 experts. Grid = 512.
__global__ __launch_bounds__(256, 2) void moe_gate(const float* __restrict__ r,
                                                   const __bf16* __restrict__ W1,
                                                   const __bf16* __restrict__ W2,
                                                   const __bf16* __restrict__ W3,
                                                   const float* __restrict__ bias,
                                                   float* __restrict__ out) {
    __shared__ float lg[64][E_DIM + 1];

    const int t    = threadIdx.x;
    const int wv   = t >> 6;
    const int lane = t & 63;
    const int lrow = lane & 15;
    const int quad = lane >> 4;
    const int row0 = blockIdx.x * 64;

    const float* ra = r + (size_t)(row0 + wv * 16 + lrow) * D_DIM + quad * 8;
    const size_t wofs = (size_t)lrow * D_DIM + quad * 8;

    f32x4 accM[4] = {};  // h1*g1              (~1 scale)
    f32x4 accD[4] = {};  // h1*g2 + h2*g1      (~2^-8 scale)
    f32x4 accL[4] = {};  // h1*g3+h2*g2+h3*g1  (~2^-16 scale)

    #pragma unroll 2
    for (int k = 0; k < D_DIM; k += 32) {
        float4 a0 = *(const float4*)(ra + k);
        float4 a1 = *(const float4*)(ra + k + 4);
        float av[8] = {a0.x, a0.y, a0.z, a0.w, a1.x, a1.y, a1.z, a1.w};
        bf16x8 A1, A2, A3;
        #pragma unroll
        for (int j = 0; j < 8; ++j) {
            float x  = av[j];
            __bf16 h1 = (__bf16)x;
            float r1 = x - (float)h1;
            __bf16 h2 = (__bf16)r1;
            float r2 = r1 - (float)h2;
            A1[j] = h1; A2[j] = h2; A3[j] = (__bf16)r2;
        }
        #pragma unroll
        for (int n = 0; n < 4; ++n) {
            size_t o = wofs + (size_t)n * 16 * D_DIM + k;
            bf16x8 B1 = *(const bf16x8*)(W1 + o);
            bf16x8 B2 = *(const bf16x8*)(W2 + o);
            bf16x8 B3 = *(const bf16x8*)(W3 + o);
            accM[n] = __builtin_amdgcn_mfma_f32_16x16x32_bf16(A1, B1, accM[n], 0, 0, 0);
            accD[n] = __builtin_amdgcn_mfma_f32_16x16x32_bf16(A1, B2, accD[n], 0, 0, 0);
            accD[n] = __builtin_amdgcn_mfma_f32_16x16x32_bf16(A2, B1, accD[n], 0, 0, 0);
            accL[n] = __builtin_amdgcn_mfma_f32_16x16x32_bf16(A1, B3, accL[n], 0, 0, 0);
            accL[n] = __builtin_amdgcn_mfma_f32_16x16x32_bf16(A2, B2, accL[n], 0, 0, 0);
            accL[n] = __builtin_amdgcn_mfma_f32_16x16x32_bf16(A3, B1, accL[n], 0, 0, 0);
        }
    }

    // C/D layout: col = lane&15, row = quad*4 + reg. Combine small-first.
    #pragma unroll
    for (int n = 0; n < 4; ++n) {
        int col = n * 16 + lrow;
        float bb = bias[col];
        #pragma unroll
        for (int i = 0; i < 4; ++i) {
            lg[wv * 16 + quad * 4 + i][col] = (accM[n][i] + (accD[n][i] + accL[n][i])) + bb;
        }
    }
    __syncthreads();

    // softmax + top-8; wave per row, lane = expert. TEMPERATURE == 1.0.
    for (int rr = wv; rr < 64; rr += 4) {
        float logit = lg[rr][lane];
        float mx = logit;
        #pragma unroll
        for (int s = 32; s >= 1; s >>= 1) mx = fmaxf(mx, __shfl_xor(mx, s));
        float ex = expf(logit - mx);
        float sm = ex;
        #pragma unroll
        for (int s = 32; s >= 1; s >>= 1) sm += __shfl_xor(sm, s);
        float soft = ex / sm;

        // top-8 on soft (monotone in logit); lowest-index tie-break = lax.top_k
        bool  sel    = false;
        float topsum = 0.0f;
        #pragma unroll
        for (int it = 0; it < TOPK; ++it) {
            float cand = sel ? -1.0f : soft;  // soft > 0 always
            float cm = cand;
            #pragma unroll
            for (int s = 32; s >= 1; s >>= 1) cm = fmaxf(cm, __shfl_xor(cm, s));
            unsigned long long ball = __ballot(cand == cm);
            int leader = __ffsll(ball) - 1;
            if (lane == leader) sel = true;
            topsum += cm;
        }
        float hard = sel ? soft / (topsum + 1e-9f) : 0.0f;

        size_t orow = (size_t)(row0 + rr) * E_DIM + lane;
        out[orow] = hard;
        out[(size_t)B_DIM * E_DIM + orow] = soft;
    }
}

extern "C" void kernel_launch(void* const* d_in, const int* in_sizes, int n_in,
                              void* d_out, int out_size, void* d_ws, size_t ws_size,
                              hipStream_t stream) {
    const float* r = (const float*)d_in[0];
    const float* W = (const float*)d_in[1];
    const float* b = (const float*)d_in[2];
    float* out = (float*)d_out;
    __bf16* W1 = (__bf16*)d_ws;                     // 3 * 262144 B = 768 KB of ws
    __bf16* W2 = W1 + (size_t)E_DIM * D_DIM;
    __bf16* W3 = W2 + (size_t)E_DIM * D_DIM;

    w_split3<<<64, 256, 0, stream>>>(W, W1, W2, W3);
    moe_gate<<<512, 256, 0, stream>>>(r, W1, W2, W3, b, out);
}

// Round 3
// 433.403 us; speedup vs baseline: 1.2220x; 1.2220x over previous
//
#include <hip/hip_runtime.h>
#include <hip/hip_bf16.h>
#include <stdint.h>

// MoE gate: logits = r @ W^T + b ; soft = softmax(logits) ; hard = top8-renorm
// r: (32768, 2048) fp32, W: (64, 2048) fp32, b: (64,) fp32
// d_out: [hard (32768*64) | soft (32768*64)] fp32
//
// Precision: exact bf16^3 split of both operands, 6 MFMA terms in 3 scale-
// class accumulators (round-2 verified: absmax 0.00195 vs 0.01625 thr).
// Perf (round-3): round-2 was latency-bound (VGPR=56 serialized 14 global
// loads/k-step; 7%/10% pipe util). Now: B staged through LDS with
// global_load_lds width=16 (zero VGPR cost, 2.8x fewer TA lines), double
// buffered, all 12 B-frags ds_read into locals before the MFMA burst, A
// prefetched one k-step ahead in registers.

#define D_DIM 2048
#define E_DIM 64
#define B_DIM 32768
#define TOPK 8

typedef __bf16 bf16x8 __attribute__((ext_vector_type(8)));
typedef float f32x4 __attribute__((ext_vector_type(4)));

// ---- prep: W fp32 -> 3 bf16 splits in workspace (3 * 131072 elems = 768 KB) ----
__global__ __launch_bounds__(256) void w_split3(const float* __restrict__ W,
                                                __bf16* __restrict__ W1,
                                                __bf16* __restrict__ W2,
                                                __bf16* __restrict__ W3) {
    int i = (blockIdx.x * 256 + threadIdx.x) * 8;  // 64 blocks
    bf16x8 o1, o2, o3;
    #pragma unroll
    for (int j = 0; j < 8; ++j) {
        float x  = W[i + j];
        __bf16 h1 = (__bf16)x;
        float r1 = x - (float)h1;          // exact
        __bf16 h2 = (__bf16)r1;
        float r2 = r1 - (float)h2;         // exact
        o1[j] = h1; o2[j] = h2; o3[j] = (__bf16)r2;
    }
    *(bf16x8*)(W1 + i) = o1;
    *(bf16x8*)(W2 + i) = o2;
    *(bf16x8*)(W3 + i) = o3;
}

// async 16B global -> LDS (per lane; LDS dest = wave-uniform base + lane*16)
__device__ __forceinline__ void gload_lds16(const void* g, void* s) {
    __builtin_amdgcn_global_load_lds(
        (const __attribute__((address_space(1))) unsigned int*)g,
        (__attribute__((address_space(3))) unsigned int*)s,
        16, 0, 0);
}

// ---- main: 6-term split GEMM + fused softmax/top-8 ----
// Block = 256 thr = 4 waves; wave owns 16 rows x 64 experts. Grid = 512.
__global__ __launch_bounds__(256) void moe_gate(const float* __restrict__ r,
                                                const __bf16* __restrict__ W1,
                                                const __bf16* __restrict__ W2,
                                                const __bf16* __restrict__ W3,
                                                const float* __restrict__ bias,
                                                float* __restrict__ out) {
    // B stage: [dbuf][split][e*32 + kc*8], e-major rows of 32 bf16 (64 B).
    // Natural lane-contiguous order for global_load_lds: thread t -> off t*16B.
    __shared__ __bf16 bstage[2][3][E_DIM * 32];      // 24 KB
    __shared__ float  lg[64][E_DIM + 1];             // 16.6 KB

    const int t    = threadIdx.x;
    const int wv   = t >> 6;
    const int lane = t & 63;
    const int lrow = lane & 15;
    const int quad = lane >> 4;
    const int row0 = blockIdx.x * 64;

    // staging source: thread t -> expert e = t>>2, k-chunk kc = t&3 (8 bf16)
    const int se  = t >> 2;
    const int skc = t & 3;
    const size_t sgo = (size_t)se * D_DIM + skc * 8;

    const float* ra = r + (size_t)(row0 + wv * 16 + lrow) * D_DIM + quad * 8;

    f32x4 accM[4] = {};  // h1*g1              (~1)
    f32x4 accD[4] = {};  // h1*g2 + h2*g1      (~2^-8)
    f32x4 accL[4] = {};  // h1*g3+h2*g2+h3*g1  (~2^-16)

    // prologue: stage k-step 0, load A(0)
    gload_lds16(W1 + sgo, &bstage[0][0][t * 8]);
    gload_lds16(W2 + sgo, &bstage[0][1][t * 8]);
    gload_lds16(W3 + sgo, &bstage[0][2][t * 8]);
    float4 a0 = *(const float4*)(ra);
    float4 a1 = *(const float4*)(ra + 4);

    for (int ks = 0; ks < D_DIM / 32; ++ks) {
        __syncthreads();  // bstage[ks&1] written; prior reads of other buf done
        const int kn = ks + 1;
        if (kn < D_DIM / 32) {  // stage next k-step into other buffer (async)
            const size_t go = sgo + (size_t)kn * 32;
            gload_lds16(W1 + go, &bstage[kn & 1][0][t * 8]);
            gload_lds16(W2 + go, &bstage[kn & 1][1][t * 8]);
            gload_lds16(W3 + go, &bstage[kn & 1][2][t * 8]);
        }

        // split current A; prefetch next A into registers
        float av[8] = {a0.x, a0.y, a0.z, a0.w, a1.x, a1.y, a1.z, a1.w};
        if (kn < D_DIM / 32) {
            a0 = *(const float4*)(ra + kn * 32);
            a1 = *(const float4*)(ra + kn * 32 + 4);
        }
        bf16x8 A1, A2, A3;
        #pragma unroll
        for (int j = 0; j < 8; ++j) {
            float x  = av[j];
            __bf16 h1 = (__bf16)x;
            float r1 = x - (float)h1;
            __bf16 h2 = (__bf16)r1;
            float r2 = r1 - (float)h2;
            A1[j] = h1; A2[j] = h2; A3[j] = (__bf16)r2;
        }

        // all 12 B fragments up front (ds_read_b128 burst, high MLP)
        const __bf16* bb = &bstage[ks & 1][0][0];
        const int fo = (quad * 8) + lrow * 32;  // within a split-tile
        bf16x8 B[3][4];
        #pragma unroll
        for (int s = 0; s < 3; ++s)
            #pragma unroll
            for (int n = 0; n < 4; ++n)
                B[s][n] = *(const bf16x8*)(bb + (size_t)s * E_DIM * 32 + n * 16 * 32 + fo);

        #pragma unroll
        for (int n = 0; n < 4; ++n) {
            accM[n] = __builtin_amdgcn_mfma_f32_16x16x32_bf16(A1, B[0][n], accM[n], 0, 0, 0);
            accD[n] = __builtin_amdgcn_mfma_f32_16x16x32_bf16(A1, B[1][n], accD[n], 0, 0, 0);
            accD[n] = __builtin_amdgcn_mfma_f32_16x16x32_bf16(A2, B[0][n], accD[n], 0, 0, 0);
            accL[n] = __builtin_amdgcn_mfma_f32_16x16x32_bf16(A1, B[2][n], accL[n], 0, 0, 0);
            accL[n] = __builtin_amdgcn_mfma_f32_16x16x32_bf16(A2, B[1][n], accL[n], 0, 0, 0);
            accL[n] = __builtin_amdgcn_mfma_f32_16x16x32_bf16(A3, B[0][n], accL[n], 0, 0, 0);
        }
    }

    // C/D layout: col = lane&15, row = quad*4 + reg. Combine small-first.
    #pragma unroll
    for (int n = 0; n < 4; ++n) {
        int col = n * 16 + lrow;
        float bb = bias[col];
        #pragma unroll
        for (int i = 0; i < 4; ++i) {
            lg[wv * 16 + quad * 4 + i][col] = (accM[n][i] + (accD[n][i] + accL[n][i])) + bb;
        }
    }
    __syncthreads();

    // softmax + top-8; wave per row, lane = expert. TEMPERATURE == 1.0.
    for (int rr = wv; rr < 64; rr += 4) {
        float logit = lg[rr][lane];
        float mx = logit;
        #pragma unroll
        for (int s = 32; s >= 1; s >>= 1) mx = fmaxf(mx, __shfl_xor(mx, s));
        float ex = expf(logit - mx);
        float sm = ex;
        #pragma unroll
        for (int s = 32; s >= 1; s >>= 1) sm += __shfl_xor(sm, s);
        float soft = ex / sm;

        // top-8 on soft (monotone in logit); lowest-index tie-break = lax.top_k
        bool  sel    = false;
        float topsum = 0.0f;
        #pragma unroll
        for (int it = 0; it < TOPK; ++it) {
            float cand = sel ? -1.0f : soft;  // soft > 0 always
            float cm = cand;
            #pragma unroll
            for (int s = 32; s >= 1; s >>= 1) cm = fmaxf(cm, __shfl_xor(cm, s));
            unsigned long long ball = __ballot(cand == cm);
            int leader = __ffsll(ball) - 1;
            if (lane == leader) sel = true;
            topsum += cm;
        }
        float hard = sel ? soft / (topsum + 1e-9f) : 0.0f;

        size_t orow = (size_t)(row0 + rr) * E_DIM + lane;
        out[orow] = hard;
        out[(size_t)B_DIM * E_DIM + orow] = soft;
    }
}

extern "C" void kernel_launch(void* const* d_in, const int* in_sizes, int n_in,
                              void* d_out, int out_size, void* d_ws, size_t ws_size,
                              hipStream_t stream) {
    const float* r = (const float*)d_in[0];
    const float* W = (const float*)d_in[1];
    const float* b = (const float*)d_in[2];
    float* out = (float*)d_out;
    __bf16* W1 = (__bf16*)d_ws;                     // 3 * 262144 B = 768 KB of ws
    __bf16* W2 = W1 + (size_t)E_DIM * D_DIM;
    __bf16* W3 = W2 + (size_t)E_DIM * D_DIM;

    w_split3<<<64, 256, 0, stream>>>(W, W1, W2, W3);
    moe_gate<<<512, 256, 0, stream>>>(r, W1, W2, W3, b, out);
}